// Round 1
// baseline (334.358 us; speedup 1.0000x reference)
//
#include <hip/hip_runtime.h>
#include <math.h>

// Problem constants (fixed by reference)
#define BB 4096
#define N_ELEC 64
#define N_NUC 16
#define FF 128
#define CUTOFF 5.0f

static constexpr long long S_SIZE = (long long)BB * N_NUC * FF;        // 8388608
static constexpr long long V_SIZE = (long long)BB * N_NUC * 3 * FF;    // 25165824
static constexpr long long E_CNT  = (long long)BB * N_NUC * N_ELEC;    // 4194304

static constexpr long long OFF_S  = 0;
static constexpr long long OFF_V  = OFF_S + S_SIZE;        // 8388608
static constexpr long long OFF_EI = OFF_V + V_SIZE;        // 33554432 (row), col at +E_CNT
static constexpr long long OFF_EA = OFF_EI + 2 * E_CNT;    // 41943040
static constexpr long long OFF_M  = OFF_EA + 3 * E_CNT;    // 54525952
// total = 58720256

// ---------------------------------------------------------------------------
// Kernel 1: float4 copy of s_nuc and v_nuc into d_out (they are contiguous in
// the output layout: s at float4-offset 0, v right after).
// ---------------------------------------------------------------------------
__global__ __launch_bounds__(256) void copy_sv_kernel(
    const float4* __restrict__ s, const float4* __restrict__ v,
    float4* __restrict__ out) {
    constexpr long long S4 = S_SIZE / 4;      // 2097152
    constexpr long long V4 = V_SIZE / 4;      // 6291456
    long long i = (long long)blockIdx.x * blockDim.x + threadIdx.x;
    if (i >= S4 + V4) return;
    out[i] = (i < S4) ? s[i] : v[i - S4];
}

// ---------------------------------------------------------------------------
// Kernel 2: one thread per edge e = (b*16 + i)*64 + j.
//   row  = b*16 + i
//   col  = b*64 + j
//   diff = coord_elec[b,j,:] - coord_nuc[i,:]
//   mask = sqrt(dot(diff,diff)) < 5.0   (same op order as jnp.linalg.norm)
// coord_nuc (48 floats) is staged to LDS; coord_elec reads are L2-resident
// (each [b,j] triple is reused by 16 threads).
// ---------------------------------------------------------------------------
__global__ __launch_bounds__(256) void edge_kernel(
    const float* __restrict__ coord_elec,   // [B, 64, 3]
    const float* __restrict__ coord_nuc,    // [16, 3]
    float* __restrict__ out) {
    __shared__ float nuc[N_NUC * 3];
    if (threadIdx.x < N_NUC * 3) nuc[threadIdx.x] = coord_nuc[threadIdx.x];
    __syncthreads();

    long long e = (long long)blockIdx.x * blockDim.x + threadIdx.x;
    if (e >= E_CNT) return;

    int b = (int)(e >> 10);        // / (16*64)
    int i = (int)((e >> 6) & 15);
    int j = (int)(e & 63);

    const float* ep = coord_elec + ((long long)b * N_ELEC + j) * 3;
    float d0 = ep[0] - nuc[i * 3 + 0];
    float d1 = ep[1] - nuc[i * 3 + 1];
    float d2 = ep[2] - nuc[i * 3 + 2];

    // edge_attr [e, 3]
    long long ea = OFF_EA + e * 3;
    out[ea + 0] = d0;
    out[ea + 1] = d1;
    out[ea + 2] = d2;

    // edge_index: row then col
    out[OFF_EI + e]         = (float)(b * N_NUC + i);
    out[OFF_EI + E_CNT + e] = (float)(b * N_ELEC + j);

    // mask
    float dist = sqrtf(d0 * d0 + d1 * d1 + d2 * d2);
    out[OFF_M + e] = (dist < CUTOFF) ? 1.0f : 0.0f;
}

extern "C" void kernel_launch(void* const* d_in, const int* in_sizes, int n_in,
                              void* d_out, int out_size, void* d_ws, size_t ws_size,
                              hipStream_t stream) {
    const float* s_nuc      = (const float*)d_in[0];
    const float* v_nuc      = (const float*)d_in[1];
    const float* coord_elec = (const float*)d_in[2];
    const float* coord_nuc  = (const float*)d_in[3];
    float* out = (float*)d_out;

    // Copy s + v (8388608 float4s total)
    constexpr long long TOT4 = (S_SIZE + V_SIZE) / 4;
    int copy_blocks = (int)((TOT4 + 255) / 256);
    copy_sv_kernel<<<copy_blocks, 256, 0, stream>>>(
        (const float4*)s_nuc, (const float4*)v_nuc, (float4*)out);

    // Edges
    int edge_blocks = (int)((E_CNT + 255) / 256);
    edge_kernel<<<edge_blocks, 256, 0, stream>>>(coord_elec, coord_nuc, out);
}

// Round 3
// 319.682 us; speedup vs baseline: 1.0459x; 1.0459x over previous
//
#include <hip/hip_runtime.h>
#include <math.h>

// Problem constants (fixed by reference)
#define BB 4096
#define N_ELEC 64
#define N_NUC 16
#define FF 128
#define CUTOFF 5.0f

// Native clang vector type — accepted by __builtin_nontemporal_{load,store}
typedef float v4f __attribute__((ext_vector_type(4)));

static constexpr long long S_SIZE = (long long)BB * N_NUC * FF;        // 8388608
static constexpr long long V_SIZE = (long long)BB * N_NUC * 3 * FF;    // 25165824
static constexpr long long E_CNT  = (long long)BB * N_NUC * N_ELEC;    // 4194304

static constexpr long long OFF_EI = S_SIZE + V_SIZE;       // 33554432 (row; col at +E_CNT)
static constexpr long long OFF_EA = OFF_EI + 2 * E_CNT;    // 41943040
static constexpr long long OFF_M  = OFF_EA + 3 * E_CNT;    // 54525952
// total = 58720256 floats = 224 MiB

static constexpr int COPY_BLOCKS = (int)((S_SIZE + V_SIZE) / 4 / 256); // 32768
static constexpr int EDGE_BLOCKS = (int)(E_CNT / 256);                 // 16384

// ---------------------------------------------------------------------------
// One fused kernel, block-range specialization:
//   blocks [0, COPY_BLOCKS)                : v4f copy of s_nuc + v_nuc
//   blocks [COPY_BLOCKS, +EDGE_BLOCKS)     : 256 edges each
// Each edge block lies fully inside one batch b (256 | 1024 edges per b).
// edge_attr is staged in LDS and written out as coalesced 16B stores.
// All output stores are nontemporal (zero reuse, 224 MiB stream).
// ---------------------------------------------------------------------------
__global__ __launch_bounds__(256) void fused_kernel(
    const v4f* __restrict__ s, const v4f* __restrict__ v,
    const float* __restrict__ coord_elec,   // [B, 64, 3]
    const float* __restrict__ coord_nuc,    // [16, 3]
    float* __restrict__ out)
{
    const int bid = blockIdx.x;
    const int t = threadIdx.x;

    if (bid < COPY_BLOCKS) {
        long long i = (long long)bid * 256 + t;
        constexpr long long S4 = S_SIZE / 4;  // 2097152
        v4f val = (i < S4) ? __builtin_nontemporal_load(&s[i])
                           : __builtin_nontemporal_load(&v[i - S4]);
        __builtin_nontemporal_store(val, &((v4f*)out)[i]);
        return;
    }

    // ---- edge path ----
    __shared__ float nuc[N_NUC * 3];      // 48
    __shared__ float elec[N_ELEC * 3];    // 192
    __shared__ float attr[256 * 3];       // 768

    const long long e0 = (long long)(bid - COPY_BLOCKS) * 256;
    const int b = (int)(e0 >> 10);        // batch index, uniform per block

    if (t < 48) nuc[t] = coord_nuc[t];
    if (t >= 64 && t < 64 + 192)
        elec[t - 64] = coord_elec[(long long)b * (N_ELEC * 3) + (t - 64)];
    __syncthreads();

    const long long e = e0 + t;
    const int i = (int)((e >> 6) & 15);   // nuc index
    const int j = t & 63;                 // elec index

    float d0 = elec[j * 3 + 0] - nuc[i * 3 + 0];
    float d1 = elec[j * 3 + 1] - nuc[i * 3 + 1];
    float d2 = elec[j * 3 + 2] - nuc[i * 3 + 2];

    attr[t * 3 + 0] = d0;
    attr[t * 3 + 1] = d1;
    attr[t * 3 + 2] = d2;

    // edge_index (row, col) + mask — lane-contiguous scalar stores (coalesced)
    __builtin_nontemporal_store((float)(b * N_NUC + i),  &out[OFF_EI + e]);
    __builtin_nontemporal_store((float)(b * N_ELEC + j), &out[OFF_EI + E_CNT + e]);
    float dist = sqrtf(d0 * d0 + d1 * d1 + d2 * d2);
    __builtin_nontemporal_store(dist < CUTOFF ? 1.0f : 0.0f, &out[OFF_M + e]);

    __syncthreads();

    // edge_attr for this block's 256 edges: 768 floats = 192 16B-stores, coalesced
    if (t < 192) {
        v4f* dst = (v4f*)(out + OFF_EA + e0 * 3);
        __builtin_nontemporal_store(((const v4f*)attr)[t], &dst[t]);
    }
}

extern "C" void kernel_launch(void* const* d_in, const int* in_sizes, int n_in,
                              void* d_out, int out_size, void* d_ws, size_t ws_size,
                              hipStream_t stream) {
    const float* s_nuc      = (const float*)d_in[0];
    const float* v_nuc      = (const float*)d_in[1];
    const float* coord_elec = (const float*)d_in[2];
    const float* coord_nuc  = (const float*)d_in[3];
    float* out = (float*)d_out;

    fused_kernel<<<COPY_BLOCKS + EDGE_BLOCKS, 256, 0, stream>>>(
        (const v4f*)s_nuc, (const v4f*)v_nuc, coord_elec, coord_nuc, out);
}